// Round 20
// baseline (126.698 us; speedup 1.0000x reference)
//
#include <hip/hip_runtime.h>
#include <hip/hip_bf16.h>
#include <math.h>

// Problem dims (fixed by reference)
#define B   32
#define P   196      // hw tokens (14x14)
#define C   768
#define NC  4096
#define HH  14
#define KSPLIT 12    // 768 / 64
#define NT  12       // K tiles per GEMM (768 / 64)
#define M6  6272     // B*P
// Packed k-tiled layout with T2 bank swizzle (R17, measured-best):
//   element (row, k) stored at X[kb][row][ k' ^ (((row>>1)&3)<<3) ]
//   (kb = k>>5, k' = k&31).  Staging is a LINEAR 4 KB copy; LDS fragment
//   reads apply the same XOR -> 2-way bank conflict (free).
#define TW  (768 * 32)    // Wt packed kb stride (elements)
#define TM  (M6 * 32)     // Tok/hdn packed kb stride (elements)

typedef _Float16 half8 __attribute__((ext_vector_type(8)));
typedef _Float16 half4 __attribute__((ext_vector_type(4)));
typedef float f32x4 __attribute__((ext_vector_type(4)));

#define GLOAD_LDS16(g, l)                                                      \
    __builtin_amdgcn_global_load_lds(                                          \
        (const __attribute__((address_space(1))) void*)(g),                    \
        (__attribute__((address_space(3))) void*)(l), 16, 0, 0)

// ---------------------------------------------------------------------------
// K1: SpaceSelfAware + space_fusion + residual + PACK (R18 version).
// ---------------------------------------------------------------------------
__global__ __launch_bounds__(256) void k_ssa(const float* __restrict__ t,
                                             _Float16* __restrict__ outP,
                                             float* __restrict__ partial) {
    const int b = blockIdx.y, cb = blockIdx.x, c0 = cb * 16;
    __shared__ float xp_[256 * 16];        // [(i+2)*16 + (j+1)][cc]  16 KB
    __shared__ float part[4][9][16];
    __shared__ float inv_norm[9][16];
    __shared__ _Float16 outT[P][16];       // 6.3 KB
    const int tid = threadIdx.x;
    const int cc = tid & 15, g = tid >> 4, wv = tid >> 6;

#pragma unroll
    for (int q = 0; q < 16; ++q) xp_[q * 256 + tid] = 0.0f;
    __syncthreads();

    for (int idx = tid; idx < 784; idx += 256) {
        const int p = idx >> 2, c = (idx & 3) * 4;
        const int i = p / HH, j = p % HH;
        *(float4*)&xp_[((i + 2) * 16 + (j + 1)) * 16 + c] =
            *(const float4*)&t[((size_t)b * P + p) * C + c0 + c];
    }
    __syncthreads();

    float s[9] = {};
    {
        int i = 0, j = g;
        if (j >= HH) { j -= HH; i = 1; }
        for (int p = g; p < P; p += 16) {
            const int base = ((i + 2) * 16 + (j + 1)) * 16 + cc;
            const float xp = xp_[base];
            const float xp2 = xp * xp;
#pragma unroll
            for (int k = 0; k < 9; ++k) {
                const int off = ((k / 3) - 2) * 16 + (k % 3) - 1;  // const
                const float nb = xp_[base + off * 16];
                s[k] += xp2 * nb * nb;
            }
            j += 2; ++i;
            if (j >= HH) { j -= HH; ++i; }
        }
    }
#pragma unroll
    for (int k = 0; k < 9; ++k) {
        float r = s[k];
        r += __shfl_xor(r, 16);
        r += __shfl_xor(r, 32);
        s[k] = r;
    }
    if ((tid & 63) < 16) {
#pragma unroll
        for (int k = 0; k < 9; ++k) part[wv][k][cc] = s[k];
    }
    __syncthreads();
    if (tid < 144) {
        const int k = tid >> 4, c2 = tid & 15;
        const float t4 = part[0][k][c2] + part[1][k][c2] +
                         part[2][k][c2] + part[3][k][c2];
        inv_norm[k][c2] = 1.0f / fmaxf(sqrtf(t4), 1e-12f);
    }
    __syncthreads();

    float invn[9];
#pragma unroll
    for (int k = 0; k < 9; ++k) invn[k] = inv_norm[k][cc];

    {
        int i = 0, j = g;
        if (j >= HH) { j -= HH; i = 1; }
        for (int p = g; p < P; p += 16) {
            const int base = ((i + 2) * 16 + (j + 1)) * 16 + cc;
            const float xp = xp_[base];
            float acc = 0.0f;
#pragma unroll
            for (int k = 0; k < 9; ++k) {
                const int off = ((k / 3) - 2) * 16 + (k % 3) - 1;
                const float v = xp * xp_[base + off * 16];
                const float u = fmaxf(v * invn[k], 1e-6f);
                acc += u * u * u;
            }
            const float val = cbrtf(acc * (1.0f / 9.0f)) + xp;
            float rs = val * val;
            rs += __shfl_xor(rs, 1);
            rs += __shfl_xor(rs, 2);
            rs += __shfl_xor(rs, 4);
            rs += __shfl_xor(rs, 8);
            outT[p][cc] = (_Float16)val;
            if (cc == 0) partial[(size_t)cb * M6 + b * P + p] = rs;
            j += 2; ++i;
            if (j >= HH) { j -= HH; ++i; }
        }
    }
    __syncthreads();
    // pack: 392 half8 stores into tokU[kb][row][swizzled slot]
    const int kb = cb >> 1, kbase = (cb & 1) * 16;
    for (int idx = tid; idx < P * 2; idx += 256) {
        const int p = idx >> 1, h = idx & 1;
        const half8 v = *(const half8*)&outT[p][h * 8];
        const int row = b * P + p;
        const int slot = ((kbase + h * 8) >> 3) ^ ((row >> 1) & 3);   // T2
        *(half8*)&outP[(size_t)kb * TM + (size_t)row * 32 + slot * 8] = v;
    }
}

// ---------------------------------------------------------------------------
// K2: merged prep — z<2: weight pack (W -> packed+swizzled f16); z==2:
// inv[row] = 1/max(sqrt(sum of 48 ssa partials), eps).
// ---------------------------------------------------------------------------
__global__ __launch_bounds__(256) void k_prep(const float* __restrict__ W1,
                                              const float* __restrict__ W2,
                                              _Float16* __restrict__ O1,
                                              _Float16* __restrict__ O2,
                                              const float* __restrict__ spart,
                                              float* __restrict__ invv) {
    if (blockIdx.z == 2) {
        const int row = (blockIdx.y * 24 + blockIdx.x) * 256 + threadIdx.x;
        if (row < M6) {
            float s = 0.0f;
#pragma unroll 8
            for (int cb = 0; cb < 48; ++cb) s += spart[(size_t)cb * M6 + row];
            invv[row] = 1.0f / fmaxf(sqrtf(s), 1e-12f);
        }
        return;
    }
    const float* W = blockIdx.z ? W2 : W1;
    _Float16* WtP = blockIdx.z ? O2 : O1;
    __shared__ float tt[32][33];
    const int k0 = blockIdx.x * 32, n0 = blockIdx.y * 32;   // kb = blockIdx.x
    const int r = threadIdx.x / 32, c = threadIdx.x % 32;
#pragma unroll
    for (int q = 0; q < 4; ++q)
        tt[r + q * 8][c] = W[(size_t)(k0 + r + q * 8) * C + n0 + c];
    __syncthreads();
    const int nl = threadIdx.x >> 3, h = threadIdx.x & 7;
    const int n = n0 + nl;
    half4 v;
#pragma unroll
    for (int j = 0; j < 4; ++j) v[j] = (_Float16)tt[h * 4 + j][nl];
    const int el = (h * 4) ^ (((n >> 1) & 3) << 3);          // T2 swizzle
    *(half4*)&WtP[(size_t)blockIdx.x * TW + (size_t)n * 32 + el] = v;
}

// ---------------------------------------------------------------------------
// K3/K4: f16 MFMA GEMM — 2-STAGE counted-vmcnt pipeline (32 KB LDS ->
// 5 blocks/CU resident; cross-round data says block concurrency is the
// lever).  64M x 64N, BK=64, grid 1176, XCD swizzle, T2 bank swizzle.
// GELU=true (fc1): acc*invv[m] + bias + exact GELU -> packed+swz f16.
// GELU=false (fc2): acc + bias -> fused GeM partials to gpart.
// ---------------------------------------------------------------------------
template <bool GELU>
__global__ __launch_bounds__(256) void k_mfma_gemm(
    const _Float16* __restrict__ TokP,  // packed (24 x M6 x 32)  B-operand
    const _Float16* __restrict__ WtP,   // packed (24 x 768 x 32) A-operand
    const float* __restrict__ bias,     // (N)
    const float* __restrict__ invv,     // (M6) or nullptr
    _Float16* __restrict__ Cout,        // packed f16 (GELU) or unused
    float* __restrict__ gpart) {        // (32 x 4 x 768) (fc2) or unused
    __shared__ _Float16 lA[2][2][64][32];  // [stage][kb][n][k'']  16 KB
    __shared__ _Float16 lB[2][2][64][32];  // [stage][kb][m][k'']  16 KB
    __shared__ float part2[2][2][64];      // [wmhalf][seg][n]  (fc2 only)
    const int tid = threadIdx.x;
    const int w = tid >> 6, l = tid & 63;
    const int l15 = l & 15, lk = l >> 4;

    // XCD swizzle: equal lid%8 (one XCD) covers one m-row's 12 n-tiles.
    const int lid = blockIdx.x;
    int vm, vn;
    if (lid < 1152) { vm = (lid / 96) * 8 + (lid & 7); vn = (lid % 96) >> 3; }
    else            { const int r = lid - 1152; vm = 96 + r / 12; vn = r % 12; }
    const int m0 = vm * 64, n0 = vn * 64;
    const int wn = (w & 1) * 32, wm = (w >> 1) * 32;

    f32x4 acc[2][2] = {};   // [fa over n][fb over m]

    // wave w stages one 4 KB chunk per stage: w<2 -> A (kb = w&1), else B
    const int kbsel = w & 1;
    const bool isB = (w >= 2);
    const _Float16* srcBase =
        isB ? (TokP + (size_t)m0 * 32) : (WtP + (size_t)n0 * 32);
    const size_t tileStride = isB ? (size_t)TM : (size_t)TW;
    _Float16* dst0 = isB ? &lB[0][kbsel][0][0] : &lA[0][kbsel][0][0];

#define ISSUE(tt, st_)                                                         \
    {   const _Float16* s_ = srcBase + (size_t)(2 * (tt) + kbsel) * tileStride;\
        _Float16* d_ = dst0 + (size_t)(st_) * 4096;                            \
        GLOAD_LDS16(s_ + l * 8,        d_ + l * 8);                            \
        GLOAD_LDS16(s_ + 512 + l * 8,  d_ + 512 + l * 8);                      \
        GLOAD_LDS16(s_ + 1024 + l * 8, d_ + 1024 + l * 8);                     \
        GLOAD_LDS16(s_ + 1536 + l * 8, d_ + 1536 + l * 8); }

    ISSUE(0, 0); ISSUE(1, 1);   // 8 loads in flight / wave

    for (int t = 0; t < NT; ++t) {
        // own-wave stage-t loads complete; stage t+1 remains in flight
        if (t < NT - 1) asm volatile("s_waitcnt vmcnt(4)" ::: "memory");
        else            asm volatile("s_waitcnt vmcnt(0)" ::: "memory");
        __builtin_amdgcn_s_barrier();          // all waves' stage-t loads done
        __builtin_amdgcn_sched_barrier(0);     // no ds_read hoisted above

        const int st = t & 1;
#pragma unroll
        for (int kk = 0; kk < 2; ++kk) {       // two 32-k sub-steps (kb tiles)
            half8 af[2], bf[2];
#pragma unroll
            for (int fa = 0; fa < 2; ++fa) {
                const int rowA = wn + fa * 16 + l15;
                const int colA = (lk ^ ((rowA >> 1) & 3)) * 8;   // T2 read
                af[fa] = *(const half8*)&lA[st][kk][rowA][colA];
            }
#pragma unroll
            for (int fb = 0; fb < 2; ++fb) {
                const int rowB = wm + fb * 16 + l15;
                const int colB = (lk ^ ((rowB >> 1) & 3)) * 8;   // T2 read
                bf[fb] = *(const half8*)&lB[st][kk][rowB][colB];
            }
#pragma unroll
            for (int fa = 0; fa < 2; ++fa)
#pragma unroll
                for (int fb = 0; fb < 2; ++fb)
                    acc[fa][fb] = __builtin_amdgcn_mfma_f32_16x16x32_f16(
                        af[fa], bf[fb], acc[fa][fb], 0, 0, 0);
        }
        asm volatile("s_waitcnt lgkmcnt(0)" ::: "memory");  // reads retired
        __builtin_amdgcn_s_barrier();          // safe to overwrite stage buf
        __builtin_amdgcn_sched_barrier(0);
        if (t < NT - 2) ISSUE(t + 2, st);      // refill; stays in flight
    }
#undef ISSUE

    // epilogue: lane holds D[n = nb + r][m], r=0..3 consecutive n
    const int b0 = m0 / P;
    const int rsplit = (b0 + 1) * P;
    float invm[2];
    if constexpr (GELU) {
#pragma unroll
        for (int fb = 0; fb < 2; ++fb)
            invm[fb] = invv[m0 + wm + fb * 16 + l15];
    }
#pragma unroll
    for (int fa = 0; fa < 2; ++fa) {
        const int nb = n0 + wn + fa * 16 + lk * 4;
        const float4 bv = *(const float4*)&bias[nb];
        if constexpr (GELU) {
#pragma unroll
            for (int fb = 0; fb < 2; ++fb) {
                const int m = m0 + wm + fb * 16 + l15;
                half4 o;
#pragma unroll
                for (int rr = 0; rr < 4; ++rr) {
                    float v = acc[fa][fb][rr] * invm[fb] + ((const float*)&bv)[rr];
                    v = 0.5f * v * (1.0f + erff(v * 0.70710678118654752f));
                    o[rr] = (_Float16)v;
                }
                const int el = (nb & 31) ^ (((m >> 1) & 3) << 3);
                *(half4*)&Cout[(size_t)(nb >> 5) * TM + (size_t)m * 32 + el] = o;
            }
        } else {
#pragma unroll
            for (int rr = 0; rr < 4; ++rr) {
                float s0 = 0.0f, s1 = 0.0f;
#pragma unroll
                for (int fb = 0; fb < 2; ++fb) {
                    const int m = m0 + wm + fb * 16 + l15;
                    const float v = acc[fa][fb][rr] + ((const float*)&bv)[rr];
                    const float u = fmaxf(v, 1e-6f);
                    const float u3 = u * u * u;
                    if (m >= rsplit) s1 += u3; else s0 += u3;
                }
                s0 += __shfl_xor(s0, 1); s0 += __shfl_xor(s0, 2);
                s0 += __shfl_xor(s0, 4); s0 += __shfl_xor(s0, 8);
                s1 += __shfl_xor(s1, 1); s1 += __shfl_xor(s1, 2);
                s1 += __shfl_xor(s1, 4); s1 += __shfl_xor(s1, 8);
                if (l15 == 0) {
                    part2[w >> 1][0][wn + fa * 16 + lk * 4 + rr] = s0;
                    part2[w >> 1][1][wn + fa * 16 + lk * 4 + rr] = s1;
                }
            }
        }
    }
    if constexpr (!GELU) {
        __syncthreads();
        if (tid < 128) {
            const int seg = tid >> 6, nn = tid & 63;
            const float tot = part2[0][seg][nn] + part2[1][seg][nn];
            if (seg == 0) {
                const int q = vm - ((b0 * 49) >> 4);   // vm - first_vm(b0)
                gpart[((size_t)b0 * 4 + q) * C + n0 + nn] = tot;
            } else if (rsplit < m0 + 64) {             // straddling block
                gpart[((size_t)(b0 + 1) * 4 + 0) * C + n0 + nn] = tot;
            }
        }
    }
}

// ---------------------------------------------------------------------------
// K6a: head GEMM stage 1 (split-K, 64 k per block) with FUSED GeM combine:
// g[b][k] = cbrt(mean of 4 fixed-order gpart slots) computed on the fly.
// grid (64, 12).
// ---------------------------------------------------------------------------
__global__ __launch_bounds__(256) void k_head1(const float* __restrict__ gpart,
                                               const float* __restrict__ W,
                                               float* __restrict__ partial) {
    const int n0 = blockIdx.x * 64;
    const int k0 = blockIdx.y * 64;
    __shared__ float gs[32][64];          // [b][kk]  8 KB
    __shared__ float part[4][32][64];     // [q][b][c] 32 KB
    const int tid = threadIdx.x;

    for (int idx = tid; idx < 32 * 64; idx += 256) {
        const int b = idx >> 6, kk = idx & 63;
        const float* gp = &gpart[((size_t)b * 4) * C + k0 + kk];
        const float s = gp[0] + gp[C] + gp[2 * C] + gp[3 * C];
        gs[b][kk] = cbrtf(s * (1.0f / (float)P));
    }
    __syncthreads();

    const int c = tid & 63, q = tid >> 6;
    float acc[32] = {};
#pragma unroll
    for (int kk = 0; kk < 16; ++kk) {
        const int k = q * 16 + kk;
        const float wv = W[(size_t)(k0 + k) * NC + n0 + c];
#pragma unroll
        for (int b = 0; b < 32; ++b) acc[b] += gs[b][k] * wv;
    }
#pragma unroll
    for (int b = 0; b < 32; ++b) part[q][b][c] = acc[b];
    __syncthreads();

    for (int o = tid; o < 32 * 64; o += 256) {
        const int b = o >> 6, cc = o & 63;
        const float v = part[0][b][cc] + part[1][b][cc] +
                        part[2][b][cc] + part[3][b][cc];
        partial[((size_t)blockIdx.y * 32 + b) * NC + n0 + cc] = v;
    }
}

// ---------------------------------------------------------------------------
// K6b: head stage 2 + output L2-norm, fused.  One block per batch.
// s[n] = hb[n] + fixed-order sum of KSPLIT partials; then normalize row.
// ---------------------------------------------------------------------------
__global__ __launch_bounds__(256) void k_head2n(const float* __restrict__ partial,
                                                const float* __restrict__ hb,
                                                float* __restrict__ out) {
    const int b = blockIdx.x;
    const int tid = threadIdx.x;
    float v[16];
    float ss = 0.0f;
#pragma unroll
    for (int q = 0; q < 16; ++q) {
        const int n = tid + q * 256;
        float s = hb[n];
#pragma unroll
        for (int ks = 0; ks < KSPLIT; ++ks)
            s += partial[((size_t)ks * 32 + b) * NC + n];
        v[q] = s;
        ss += s * s;
    }
    __shared__ float psum[4];
    __shared__ float inv;
#pragma unroll
    for (int off = 32; off > 0; off >>= 1) ss += __shfl_xor(ss, off);
    if ((tid & 63) == 0) psum[tid >> 6] = ss;
    __syncthreads();
    if (tid == 0)
        inv = 1.0f / fmaxf(sqrtf(psum[0] + psum[1] + psum[2] + psum[3]), 1e-12f);
    __syncthreads();
    float* r = out + (size_t)b * NC;
#pragma unroll
    for (int q = 0; q < 16; ++q) r[tid + q * 256] = v[q] * inv;
}

// ---------------------------------------------------------------------------
extern "C" void kernel_launch(void* const* d_in, const int* in_sizes, int n_in,
                              void* d_out, int out_size, void* d_ws, size_t ws_size,
                              hipStream_t stream) {
    const float* patch  = (const float*)d_in[0];
    const float* fc1_w  = (const float*)d_in[1];
    const float* fc1_b  = (const float*)d_in[2];
    const float* fc2_w  = (const float*)d_in[3];
    const float* fc2_b  = (const float*)d_in[4];
    const float* head_w = (const float*)d_in[5];
    const float* head_b = (const float*)d_in[6];
    float* out = (float*)d_out;

    const size_t big = (size_t)B * P * C;        // 4,816,896 elements
    _Float16* tokU  = (_Float16*)d_ws;           // [big] f16 packed+swz (unnorm)
    _Float16* hdnP  = tokU + big;                // [big] f16 packed+swz
    _Float16* wt1   = hdnP + big;                // [768*768] f16 packed+swz
    _Float16* wt2   = wt1 + C * C;               // [768*768] f16 packed+swz
    float*    spart = (float*)(wt2 + C * C);     // [48*M6] row-sumsq partials
    float*    invv  = spart + 48 * (size_t)M6;   // [M6]
    float*    gpart = invv + M6;                 // [32*4*768] f32
    float*    hpart = gpart + (size_t)B * 4 * C; // [KSPLIT*32*4096] f32

    // K1: SSA + fusion + residual -> tokU (packed f16) + spart
    k_ssa<<<dim3(48, B), dim3(256), 0, stream>>>(patch, tokU, spart);
    // K2: weight packs (z<2) + row inverse norms (z==2)
    k_prep<<<dim3(C / 32, C / 32, 3), dim3(256), 0, stream>>>(
        fc1_w, fc2_w, wt1, wt2, spart, invv);
    // K3: fc1 (deferred norm via invv) + gelu -> hdnP (f16 packed+swz)
    k_mfma_gemm<true><<<dim3(1176), dim3(256), 0, stream>>>(
        tokU, wt1, fc1_b, invv, hdnP, nullptr);
    // K4: fc2 + fused GeM partials -> gpart (no token output)
    k_mfma_gemm<false><<<dim3(1176), dim3(256), 0, stream>>>(
        hdnP, wt2, fc2_b, nullptr, nullptr, gpart);
    // K6a: head GEMM stage 1 (g computed on the fly from gpart)
    k_head1<<<dim3(NC / 64, KSPLIT), dim3(256), 0, stream>>>(
        gpart, head_w, hpart);
    // K6b: head stage 2 + output norm
    k_head2n<<<dim3(B), dim3(256), 0, stream>>>(hpart, head_b, out);
}

// Round 21
// 82.903 us; speedup vs baseline: 1.5283x; 1.5283x over previous
//
#include <hip/hip_runtime.h>
#include <hip/hip_bf16.h>
#include <math.h>

// Problem dims (fixed by reference)
#define B   32
#define P   196      // hw tokens (14x14)
#define C   768
#define NC  4096
#define HH  14
#define KSPLIT 12    // 768 / 64
#define NT  12       // K tiles per GEMM (768 / 64)
#define M6  6272     // B*P
// Packed k-tiled layout with T2 bank swizzle (R17, measured-best):
//   element (row, k) stored at X[kb][row][ k' ^ (((row>>1)&3)<<3) ]
//   (kb = k>>5, k' = k&31).  Staging is a LINEAR 4 KB copy; LDS fragment
//   reads apply the same XOR -> 2-way bank conflict (free).
#define TW  (768 * 32)    // Wt packed kb stride (elements)
#define TM  (M6 * 32)     // Tok/hdn packed kb stride (elements)

typedef _Float16 half8 __attribute__((ext_vector_type(8)));
typedef _Float16 half4 __attribute__((ext_vector_type(4)));
typedef float f32x4 __attribute__((ext_vector_type(4)));

#define GLOAD_LDS16(g, l)                                                      \
    __builtin_amdgcn_global_load_lds(                                          \
        (const __attribute__((address_space(1))) void*)(g),                    \
        (__attribute__((address_space(3))) void*)(l), 16, 0, 0)

// ---------------------------------------------------------------------------
// K1: SpaceSelfAware + space_fusion + residual + PACK.
// ---------------------------------------------------------------------------
__global__ __launch_bounds__(256) void k_ssa(const float* __restrict__ t,
                                             _Float16* __restrict__ outP,
                                             float* __restrict__ partial) {
    const int b = blockIdx.y, cb = blockIdx.x, c0 = cb * 16;
    __shared__ float xp_[256 * 16];        // [(i+2)*16 + (j+1)][cc]  16 KB
    __shared__ float part[4][9][16];
    __shared__ float inv_norm[9][16];
    __shared__ _Float16 outT[P][16];       // 6.3 KB
    const int tid = threadIdx.x;
    const int cc = tid & 15, g = tid >> 4, wv = tid >> 6;

#pragma unroll
    for (int q = 0; q < 16; ++q) xp_[q * 256 + tid] = 0.0f;
    __syncthreads();

    for (int idx = tid; idx < 784; idx += 256) {
        const int p = idx >> 2, c = (idx & 3) * 4;
        const int i = p / HH, j = p % HH;
        *(float4*)&xp_[((i + 2) * 16 + (j + 1)) * 16 + c] =
            *(const float4*)&t[((size_t)b * P + p) * C + c0 + c];
    }
    __syncthreads();

    float s[9] = {};
    {
        int i = 0, j = g;
        if (j >= HH) { j -= HH; i = 1; }
        for (int p = g; p < P; p += 16) {
            const int base = ((i + 2) * 16 + (j + 1)) * 16 + cc;
            const float xp = xp_[base];
            const float xp2 = xp * xp;
#pragma unroll
            for (int k = 0; k < 9; ++k) {
                const int off = ((k / 3) - 2) * 16 + (k % 3) - 1;  // const
                const float nb = xp_[base + off * 16];
                s[k] += xp2 * nb * nb;
            }
            j += 2; ++i;
            if (j >= HH) { j -= HH; ++i; }
        }
    }
#pragma unroll
    for (int k = 0; k < 9; ++k) {
        float r = s[k];
        r += __shfl_xor(r, 16);
        r += __shfl_xor(r, 32);
        s[k] = r;
    }
    if ((tid & 63) < 16) {
#pragma unroll
        for (int k = 0; k < 9; ++k) part[wv][k][cc] = s[k];
    }
    __syncthreads();
    if (tid < 144) {
        const int k = tid >> 4, c2 = tid & 15;
        const float t4 = part[0][k][c2] + part[1][k][c2] +
                         part[2][k][c2] + part[3][k][c2];
        inv_norm[k][c2] = 1.0f / fmaxf(sqrtf(t4), 1e-12f);
    }
    __syncthreads();

    float invn[9];
#pragma unroll
    for (int k = 0; k < 9; ++k) invn[k] = inv_norm[k][cc];

    {
        int i = 0, j = g;
        if (j >= HH) { j -= HH; i = 1; }
        for (int p = g; p < P; p += 16) {
            const int base = ((i + 2) * 16 + (j + 1)) * 16 + cc;
            const float xp = xp_[base];
            float acc = 0.0f;
#pragma unroll
            for (int k = 0; k < 9; ++k) {
                const int off = ((k / 3) - 2) * 16 + (k % 3) - 1;
                const float v = xp * xp_[base + off * 16];
                const float u = fmaxf(v * invn[k], 1e-6f);
                acc += u * u * u;
            }
            const float val = cbrtf(acc * (1.0f / 9.0f)) + xp;
            float rs = val * val;
            rs += __shfl_xor(rs, 1);
            rs += __shfl_xor(rs, 2);
            rs += __shfl_xor(rs, 4);
            rs += __shfl_xor(rs, 8);
            outT[p][cc] = (_Float16)val;
            if (cc == 0) partial[(size_t)cb * M6 + b * P + p] = rs;
            j += 2; ++i;
            if (j >= HH) { j -= HH; ++i; }
        }
    }
    __syncthreads();
    // pack: 392 half8 stores into tokU[kb][row][swizzled slot]
    const int kb = cb >> 1, kbase = (cb & 1) * 16;
    for (int idx = tid; idx < P * 2; idx += 256) {
        const int p = idx >> 1, h = idx & 1;
        const half8 v = *(const half8*)&outT[p][h * 8];
        const int row = b * P + p;
        const int slot = ((kbase + h * 8) >> 3) ^ ((row >> 1) & 3);   // T2
        *(half8*)&outP[(size_t)kb * TM + (size_t)row * 32 + slot * 8] = v;
    }
}

// ---------------------------------------------------------------------------
// K2: merged prep — z<2: weight pack (W -> packed+swizzled f16); z==2:
// inv[row] = 1/max(sqrt(sum of 48 ssa partials), eps).
// ---------------------------------------------------------------------------
__global__ __launch_bounds__(256) void k_prep(const float* __restrict__ W1,
                                              const float* __restrict__ W2,
                                              _Float16* __restrict__ O1,
                                              _Float16* __restrict__ O2,
                                              const float* __restrict__ spart,
                                              float* __restrict__ invv) {
    if (blockIdx.z == 2) {
        const int row = (blockIdx.y * 24 + blockIdx.x) * 256 + threadIdx.x;
        if (row < M6) {
            float s = 0.0f;
#pragma unroll 8
            for (int cb = 0; cb < 48; ++cb) s += spart[(size_t)cb * M6 + row];
            invv[row] = 1.0f / fmaxf(sqrtf(s), 1e-12f);
        }
        return;
    }
    const float* W = blockIdx.z ? W2 : W1;
    _Float16* WtP = blockIdx.z ? O2 : O1;
    __shared__ float tt[32][33];
    const int k0 = blockIdx.x * 32, n0 = blockIdx.y * 32;   // kb = blockIdx.x
    const int r = threadIdx.x / 32, c = threadIdx.x % 32;
#pragma unroll
    for (int q = 0; q < 4; ++q)
        tt[r + q * 8][c] = W[(size_t)(k0 + r + q * 8) * C + n0 + c];
    __syncthreads();
    const int nl = threadIdx.x >> 3, h = threadIdx.x & 7;
    const int n = n0 + nl;
    half4 v;
#pragma unroll
    for (int j = 0; j < 4; ++j) v[j] = (_Float16)tt[h * 4 + j][nl];
    const int el = (h * 4) ^ (((n >> 1) & 3) << 3);          // T2 swizzle
    *(half4*)&WtP[(size_t)blockIdx.x * TW + (size_t)n * 32 + el] = v;
}

// ---------------------------------------------------------------------------
// K3/K4: f16 MFMA GEMM — measured-best 3-stage counted-vmcnt pipeline,
// 64M x 64N, BK=64, grid 1176, XCD swizzle, T2 bank swizzle (R17/R18).
// GELU=true (fc1): acc*invv[m] + bias + exact GELU -> packed+swz f16.
// GELU=false (fc2): acc + bias -> fused GeM partials to gpart.
// ---------------------------------------------------------------------------
template <bool GELU>
__global__ __launch_bounds__(256) void k_mfma_gemm(
    const _Float16* __restrict__ TokP,  // packed (24 x M6 x 32)  B-operand
    const _Float16* __restrict__ WtP,   // packed (24 x 768 x 32) A-operand
    const float* __restrict__ bias,     // (N)
    const float* __restrict__ invv,     // (M6) or nullptr
    _Float16* __restrict__ Cout,        // packed f16 (GELU) or unused
    float* __restrict__ gpart) {        // (32 x 4 x 768) (fc2) or unused
    __shared__ _Float16 lA[3][2][64][32];  // [buf][kb][n][k'']
    __shared__ _Float16 lB[3][2][64][32];  // [buf][kb][m][k'']
    __shared__ float part2[2][2][64];      // [wmhalf][seg][n]  (fc2 only)
    const int tid = threadIdx.x;
    const int w = tid >> 6, l = tid & 63;
    const int l15 = l & 15, lk = l >> 4;

    // XCD swizzle: equal lid%8 (one XCD) covers one m-row's 12 n-tiles.
    const int lid = blockIdx.x;
    int vm, vn;
    if (lid < 1152) { vm = (lid / 96) * 8 + (lid & 7); vn = (lid % 96) >> 3; }
    else            { const int r = lid - 1152; vm = 96 + r / 12; vn = r % 12; }
    const int m0 = vm * 64, n0 = vn * 64;
    const int wn = (w & 1) * 32, wm = (w >> 1) * 32;

    f32x4 acc[2][2] = {};   // [fa over n][fb over m]

    // wave w stages one 4 KB chunk per stage: w<2 -> A (kb = w&1), else B
    const int kbsel = w & 1;
    const bool isB = (w >= 2);
    const _Float16* srcBase =
        isB ? (TokP + (size_t)m0 * 32) : (WtP + (size_t)n0 * 32);
    const size_t tileStride = isB ? (size_t)TM : (size_t)TW;
    _Float16* dst0 = isB ? &lB[0][kbsel][0][0] : &lA[0][kbsel][0][0];

#define ISSUE(tt, bf_)                                                         \
    {   const _Float16* s_ = srcBase + (size_t)(2 * (tt) + kbsel) * tileStride;\
        _Float16* d_ = dst0 + (size_t)(bf_) * 4096;                            \
        GLOAD_LDS16(s_ + l * 8,        d_ + l * 8);                            \
        GLOAD_LDS16(s_ + 512 + l * 8,  d_ + 512 + l * 8);                      \
        GLOAD_LDS16(s_ + 1024 + l * 8, d_ + 1024 + l * 8);                     \
        GLOAD_LDS16(s_ + 1536 + l * 8, d_ + 1536 + l * 8); }

    ISSUE(0, 0); ISSUE(1, 1); ISSUE(2, 2);   // 12 loads in flight / wave

    for (int t = 0; t < NT; ++t) {
        // own-wave tile-t loads complete; t+1, t+2 remain in flight
        if (t < NT - 2)       asm volatile("s_waitcnt vmcnt(8)" ::: "memory");
        else if (t == NT - 2) asm volatile("s_waitcnt vmcnt(4)" ::: "memory");
        else                  asm volatile("s_waitcnt vmcnt(0)" ::: "memory");
        __builtin_amdgcn_s_barrier();          // all waves' tile-t loads done
        __builtin_amdgcn_sched_barrier(0);     // no ds_read hoisted above

        const int buf = t % 3;
#pragma unroll
        for (int kk = 0; kk < 2; ++kk) {       // two 32-k sub-steps (kb tiles)
            half8 af[2], bf[2];
#pragma unroll
            for (int fa = 0; fa < 2; ++fa) {
                const int rowA = wn + fa * 16 + l15;
                const int colA = (lk ^ ((rowA >> 1) & 3)) * 8;   // T2 read
                af[fa] = *(const half8*)&lA[buf][kk][rowA][colA];
            }
#pragma unroll
            for (int fb = 0; fb < 2; ++fb) {
                const int rowB = wm + fb * 16 + l15;
                const int colB = (lk ^ ((rowB >> 1) & 3)) * 8;   // T2 read
                bf[fb] = *(const half8*)&lB[buf][kk][rowB][colB];
            }
#pragma unroll
            for (int fa = 0; fa < 2; ++fa)
#pragma unroll
                for (int fb = 0; fb < 2; ++fb)
                    acc[fa][fb] = __builtin_amdgcn_mfma_f32_16x16x32_f16(
                        af[fa], bf[fb], acc[fa][fb], 0, 0, 0);
        }
        asm volatile("s_waitcnt lgkmcnt(0)" ::: "memory");  // reads retired
        __builtin_amdgcn_s_barrier();          // safe to overwrite buf
        __builtin_amdgcn_sched_barrier(0);
        if (t < NT - 3) ISSUE(t + 3, buf);     // refill; stays in flight
    }
#undef ISSUE

    // epilogue: lane holds D[n = nb + r][m], r=0..3 consecutive n
    const int b0 = m0 / P;
    const int rsplit = (b0 + 1) * P;
    float invm[2];
    if constexpr (GELU) {
#pragma unroll
        for (int fb = 0; fb < 2; ++fb)
            invm[fb] = invv[m0 + wm + fb * 16 + l15];
    }
#pragma unroll
    for (int fa = 0; fa < 2; ++fa) {
        const int nb = n0 + wn + fa * 16 + lk * 4;
        const float4 bv = *(const float4*)&bias[nb];
        if constexpr (GELU) {
#pragma unroll
            for (int fb = 0; fb < 2; ++fb) {
                const int m = m0 + wm + fb * 16 + l15;
                half4 o;
#pragma unroll
                for (int rr = 0; rr < 4; ++rr) {
                    float v = acc[fa][fb][rr] * invm[fb] + ((const float*)&bv)[rr];
                    v = 0.5f * v * (1.0f + erff(v * 0.70710678118654752f));
                    o[rr] = (_Float16)v;
                }
                const int el = (nb & 31) ^ (((m >> 1) & 3) << 3);
                *(half4*)&Cout[(size_t)(nb >> 5) * TM + (size_t)m * 32 + el] = o;
            }
        } else {
#pragma unroll
            for (int rr = 0; rr < 4; ++rr) {
                float s0 = 0.0f, s1 = 0.0f;
#pragma unroll
                for (int fb = 0; fb < 2; ++fb) {
                    const int m = m0 + wm + fb * 16 + l15;
                    const float v = acc[fa][fb][rr] + ((const float*)&bv)[rr];
                    const float u = fmaxf(v, 1e-6f);
                    const float u3 = u * u * u;
                    if (m >= rsplit) s1 += u3; else s0 += u3;
                }
                s0 += __shfl_xor(s0, 1); s0 += __shfl_xor(s0, 2);
                s0 += __shfl_xor(s0, 4); s0 += __shfl_xor(s0, 8);
                s1 += __shfl_xor(s1, 1); s1 += __shfl_xor(s1, 2);
                s1 += __shfl_xor(s1, 4); s1 += __shfl_xor(s1, 8);
                if (l15 == 0) {
                    part2[w >> 1][0][wn + fa * 16 + lk * 4 + rr] = s0;
                    part2[w >> 1][1][wn + fa * 16 + lk * 4 + rr] = s1;
                }
            }
        }
    }
    if constexpr (!GELU) {
        __syncthreads();
        if (tid < 128) {
            const int seg = tid >> 6, nn = tid & 63;
            const float tot = part2[0][seg][nn] + part2[1][seg][nn];
            if (seg == 0) {
                const int q = vm - ((b0 * 49) >> 4);   // vm - first_vm(b0)
                gpart[((size_t)b0 * 4 + q) * C + n0 + nn] = tot;
            } else if (rsplit < m0 + 64) {             // straddling block
                gpart[((size_t)(b0 + 1) * 4 + 0) * C + n0 + nn] = tot;
            }
        }
    }
}

// ---------------------------------------------------------------------------
// K6a: head GEMM stage 1 (split-K, 64 k per block) with FUSED GeM combine:
// g[b][k] = cbrt(mean of 4 fixed-order gpart slots) computed on the fly.
// grid (64, 12).
// ---------------------------------------------------------------------------
__global__ __launch_bounds__(256) void k_head1(const float* __restrict__ gpart,
                                               const float* __restrict__ W,
                                               float* __restrict__ partial) {
    const int n0 = blockIdx.x * 64;
    const int k0 = blockIdx.y * 64;
    __shared__ float gs[32][64];          // [b][kk]  8 KB
    __shared__ float part[4][32][64];     // [q][b][c] 32 KB
    const int tid = threadIdx.x;

    for (int idx = tid; idx < 32 * 64; idx += 256) {
        const int b = idx >> 6, kk = idx & 63;
        const float* gp = &gpart[((size_t)b * 4) * C + k0 + kk];
        const float s = gp[0] + gp[C] + gp[2 * C] + gp[3 * C];
        gs[b][kk] = cbrtf(s * (1.0f / (float)P));
    }
    __syncthreads();

    const int c = tid & 63, q = tid >> 6;
    float acc[32] = {};
#pragma unroll
    for (int kk = 0; kk < 16; ++kk) {
        const int k = q * 16 + kk;
        const float wv = W[(size_t)(k0 + k) * NC + n0 + c];
#pragma unroll
        for (int b = 0; b < 32; ++b) acc[b] += gs[b][k] * wv;
    }
#pragma unroll
    for (int b = 0; b < 32; ++b) part[q][b][c] = acc[b];
    __syncthreads();

    for (int o = tid; o < 32 * 64; o += 256) {
        const int b = o >> 6, cc = o & 63;
        const float v = part[0][b][cc] + part[1][b][cc] +
                        part[2][b][cc] + part[3][b][cc];
        partial[((size_t)blockIdx.y * 32 + b) * NC + n0 + cc] = v;
    }
}

// ---------------------------------------------------------------------------
// K6b: head stage 2: fixed-order sum of KSPLIT partials + bias.
// grid (16, 32) = 512 blocks (parallelism matters: one-block-per-batch
// fusion was a 49 us latency stall in R20).
// ---------------------------------------------------------------------------
__global__ __launch_bounds__(256) void k_head2(const float* __restrict__ partial,
                                               const float* __restrict__ hb,
                                               float* __restrict__ out) {
    const int n = blockIdx.x * 256 + threadIdx.x;
    const int b = blockIdx.y;
    float s = hb[n];
#pragma unroll
    for (int ks = 0; ks < KSPLIT; ++ks)
        s += partial[((size_t)ks * 32 + b) * NC + n];
    out[(size_t)b * NC + n] = s;
}

// ---------------------------------------------------------------------------
// K7: L2-normalize each batch row of out (4096) in place.
// ---------------------------------------------------------------------------
__global__ __launch_bounds__(256) void k_outnorm(float* __restrict__ out) {
    const int b = blockIdx.x;
    float* r = out + (size_t)b * NC;
    const int tid = threadIdx.x;
    float v[16];
    float s = 0.0f;
#pragma unroll
    for (int q = 0; q < 16; ++q) {
        v[q] = r[tid + q * 256];
        s += v[q] * v[q];
    }
    __shared__ float partial[4];
    __shared__ float inv;
#pragma unroll
    for (int off = 32; off > 0; off >>= 1) s += __shfl_xor(s, off);
    if ((tid & 63) == 0) partial[tid >> 6] = s;
    __syncthreads();
    if (tid == 0)
        inv = 1.0f / fmaxf(sqrtf(partial[0] + partial[1] + partial[2] + partial[3]), 1e-12f);
    __syncthreads();
#pragma unroll
    for (int q = 0; q < 16; ++q) r[tid + q * 256] = v[q] * inv;
}

// ---------------------------------------------------------------------------
extern "C" void kernel_launch(void* const* d_in, const int* in_sizes, int n_in,
                              void* d_out, int out_size, void* d_ws, size_t ws_size,
                              hipStream_t stream) {
    const float* patch  = (const float*)d_in[0];
    const float* fc1_w  = (const float*)d_in[1];
    const float* fc1_b  = (const float*)d_in[2];
    const float* fc2_w  = (const float*)d_in[3];
    const float* fc2_b  = (const float*)d_in[4];
    const float* head_w = (const float*)d_in[5];
    const float* head_b = (const float*)d_in[6];
    float* out = (float*)d_out;

    const size_t big = (size_t)B * P * C;        // 4,816,896 elements
    _Float16* tokU  = (_Float16*)d_ws;           // [big] f16 packed+swz (unnorm)
    _Float16* hdnP  = tokU + big;                // [big] f16 packed+swz
    _Float16* wt1   = hdnP + big;                // [768*768] f16 packed+swz
    _Float16* wt2   = wt1 + C * C;               // [768*768] f16 packed+swz
    float*    spart = (float*)(wt2 + C * C);     // [48*M6] row-sumsq partials
    float*    invv  = spart + 48 * (size_t)M6;   // [M6]
    float*    gpart = invv + M6;                 // [32*4*768] f32
    float*    hpart = gpart + (size_t)B * 4 * C; // [KSPLIT*32*4096] f32

    // K1: SSA + fusion + residual -> tokU (packed f16) + spart
    k_ssa<<<dim3(48, B), dim3(256), 0, stream>>>(patch, tokU, spart);
    // K2: weight packs (z<2) + row inverse norms (z==2)
    k_prep<<<dim3(C / 32, C / 32, 3), dim3(256), 0, stream>>>(
        fc1_w, fc2_w, wt1, wt2, spart, invv);
    // K3: fc1 (deferred norm via invv) + gelu -> hdnP (f16 packed+swz)
    k_mfma_gemm<true><<<dim3(1176), dim3(256), 0, stream>>>(
        tokU, wt1, fc1_b, invv, hdnP, nullptr);
    // K4: fc2 + fused GeM partials -> gpart (no token output)
    k_mfma_gemm<false><<<dim3(1176), dim3(256), 0, stream>>>(
        hdnP, wt2, fc2_b, nullptr, nullptr, gpart);
    // K6a: head GEMM stage 1 (g computed on the fly from gpart)
    k_head1<<<dim3(NC / 64, KSPLIT), dim3(256), 0, stream>>>(
        gpart, head_w, hpart);
    // K6b: head stage 2 -> out
    k_head2<<<dim3(NC / 256, B), dim3(256), 0, stream>>>(hpart, head_b, out);
    // K7: normalize rows of out
    k_outnorm<<<dim3(B), dim3(256), 0, stream>>>(out);
}

// Round 22
// 82.006 us; speedup vs baseline: 1.5450x; 1.0109x over previous
//
#include <hip/hip_runtime.h>
#include <hip/hip_bf16.h>
#include <math.h>

// Problem dims (fixed by reference)
#define B   32
#define P   196      // hw tokens (14x14)
#define C   768
#define NC  4096
#define HH  14
#define KSPLIT 12    // 768 / 64
#define NT  12       // K tiles per GEMM (768 / 64)
#define M6  6272     // B*P
// Packed k-tiled layout with T2 bank swizzle (R17, measured-best):
//   element (row, k) stored at X[kb][row][ k' ^ (((row>>1)&3)<<3) ]
//   (kb = k>>5, k' = k&31).  Staging is a LINEAR 4 KB copy; LDS fragment
//   reads apply the same XOR -> 2-way bank conflict (free).
#define TW  (768 * 32)    // Wt packed kb stride (elements)
#define TM  (M6 * 32)     // Tok/hdn packed kb stride (elements)

typedef _Float16 half8 __attribute__((ext_vector_type(8)));
typedef _Float16 half4 __attribute__((ext_vector_type(4)));
typedef float f32x4 __attribute__((ext_vector_type(4)));

#define GLOAD_LDS16(g, l)                                                      \
    __builtin_amdgcn_global_load_lds(                                          \
        (const __attribute__((address_space(1))) void*)(g),                    \
        (__attribute__((address_space(3))) void*)(l), 16, 0, 0)

// ---------------------------------------------------------------------------
// K1 (merged): z=0 -> SpaceSelfAware + space_fusion + residual + PACK;
// z=1 -> weight pack for both MLP matrices (data-independent of SSA, runs
// concurrently in the same launch).  Pack branch overlays SSA's LDS.
// ---------------------------------------------------------------------------
__global__ __launch_bounds__(256) void k_ssa(const float* __restrict__ t,
                                             _Float16* __restrict__ outP,
                                             float* __restrict__ spart,
                                             const float* __restrict__ W1,
                                             const float* __restrict__ W2,
                                             _Float16* __restrict__ O1,
                                             _Float16* __restrict__ O2) {
    __shared__ float xp_[256 * 16];        // [(i+2)*16 + (j+1)][cc]  16 KB
    __shared__ float part[4][9][16];
    __shared__ float inv_norm[9][16];
    __shared__ _Float16 outT[P][16];       // 6.3 KB
    const int tid = threadIdx.x;

    if (blockIdx.z == 1) {                 // ---- weight pack branch ----
        const int idx = blockIdx.y * 48 + blockIdx.x;
        if (idx >= 1152) return;
        const bool second = idx >= 576;
        const int id2 = second ? idx - 576 : idx;
        const float* W = second ? W2 : W1;
        _Float16* WtP = second ? O2 : O1;
        const int kb = id2 / 24, nb2 = id2 % 24;
        const int k0 = kb * 32, n0 = nb2 * 32;
        float (*tt)[33] = (float (*)[33])xp_;   // overlay 32x33 f32
        const int r = tid / 32, c = tid % 32;
#pragma unroll
        for (int q = 0; q < 4; ++q)
            tt[r + q * 8][c] = W[(size_t)(k0 + r + q * 8) * C + n0 + c];
        __syncthreads();
        const int nl = tid >> 3, h = tid & 7;
        const int n = n0 + nl;
        half4 v;
#pragma unroll
        for (int j = 0; j < 4; ++j) v[j] = (_Float16)tt[h * 4 + j][nl];
        const int el = (h * 4) ^ (((n >> 1) & 3) << 3);      // T2 swizzle
        *(half4*)&WtP[(size_t)kb * TW + (size_t)n * 32 + el] = v;
        return;
    }

    // ---- SSA branch ----
    const int b = blockIdx.y, cb = blockIdx.x, c0 = cb * 16;
    const int cc = tid & 15, g = tid >> 4, wv = tid >> 6;

#pragma unroll
    for (int q = 0; q < 16; ++q) xp_[q * 256 + tid] = 0.0f;
    __syncthreads();

    for (int idx = tid; idx < 784; idx += 256) {
        const int p = idx >> 2, c = (idx & 3) * 4;
        const int i = p / HH, j = p % HH;
        *(float4*)&xp_[((i + 2) * 16 + (j + 1)) * 16 + c] =
            *(const float4*)&t[((size_t)b * P + p) * C + c0 + c];
    }
    __syncthreads();

    float s[9] = {};
    {
        int i = 0, j = g;
        if (j >= HH) { j -= HH; i = 1; }
        for (int p = g; p < P; p += 16) {
            const int base = ((i + 2) * 16 + (j + 1)) * 16 + cc;
            const float xp = xp_[base];
            const float xp2 = xp * xp;
#pragma unroll
            for (int k = 0; k < 9; ++k) {
                const int off = ((k / 3) - 2) * 16 + (k % 3) - 1;  // const
                const float nb = xp_[base + off * 16];
                s[k] += xp2 * nb * nb;
            }
            j += 2; ++i;
            if (j >= HH) { j -= HH; ++i; }
        }
    }
#pragma unroll
    for (int k = 0; k < 9; ++k) {
        float r = s[k];
        r += __shfl_xor(r, 16);
        r += __shfl_xor(r, 32);
        s[k] = r;
    }
    if ((tid & 63) < 16) {
#pragma unroll
        for (int k = 0; k < 9; ++k) part[wv][k][cc] = s[k];
    }
    __syncthreads();
    if (tid < 144) {
        const int k = tid >> 4, c2 = tid & 15;
        const float t4 = part[0][k][c2] + part[1][k][c2] +
                         part[2][k][c2] + part[3][k][c2];
        inv_norm[k][c2] = 1.0f / fmaxf(sqrtf(t4), 1e-12f);
    }
    __syncthreads();

    float invn[9];
#pragma unroll
    for (int k = 0; k < 9; ++k) invn[k] = inv_norm[k][cc];

    {
        int i = 0, j = g;
        if (j >= HH) { j -= HH; i = 1; }
        for (int p = g; p < P; p += 16) {
            const int base = ((i + 2) * 16 + (j + 1)) * 16 + cc;
            const float xp = xp_[base];
            float acc = 0.0f;
#pragma unroll
            for (int k = 0; k < 9; ++k) {
                const int off = ((k / 3) - 2) * 16 + (k % 3) - 1;
                const float v = xp * xp_[base + off * 16];
                const float u = fmaxf(v * invn[k], 1e-6f);
                acc += u * u * u;
            }
            const float val = cbrtf(acc * (1.0f / 9.0f)) + xp;
            float rs = val * val;
            rs += __shfl_xor(rs, 1);
            rs += __shfl_xor(rs, 2);
            rs += __shfl_xor(rs, 4);
            rs += __shfl_xor(rs, 8);
            outT[p][cc] = (_Float16)val;
            if (cc == 0) spart[(size_t)cb * M6 + b * P + p] = rs;
            j += 2; ++i;
            if (j >= HH) { j -= HH; ++i; }
        }
    }
    __syncthreads();
    // pack: 392 half8 stores into tokU[kb][row][swizzled slot]
    const int kb = cb >> 1, kbase = (cb & 1) * 16;
    for (int idx = tid; idx < P * 2; idx += 256) {
        const int p = idx >> 1, h = idx & 1;
        const half8 v = *(const half8*)&outT[p][h * 8];
        const int row = b * P + p;
        const int slot = ((kbase + h * 8) >> 3) ^ ((row >> 1) & 3);   // T2
        *(half8*)&outP[(size_t)kb * TM + (size_t)row * 32 + slot * 8] = v;
    }
}

// ---------------------------------------------------------------------------
// K3/K4: f16 MFMA GEMM — measured-best 3-stage counted-vmcnt pipeline,
// 64M x 64N, BK=64, grid 1176, XCD swizzle, T2 bank swizzle (R17/R18).
// GELU=true (fc1): computes the 64-row inv-norm slice INLINE from spart
// (same fixed-order 48-term sum as the old k_prep) before the pipeline
// starts (loads drained by a __syncthreads BEFORE the first ISSUE, so the
// manual counted vmcnt still sees exactly the gload_lds queue); epilogue:
// acc*inv[m] + bias + exact GELU -> packed+swz f16.
// GELU=false (fc2): acc + bias -> fused GeM partials to gpart.
// ---------------------------------------------------------------------------
template <bool GELU>
__global__ __launch_bounds__(256) void k_mfma_gemm(
    const _Float16* __restrict__ TokP,  // packed (24 x M6 x 32)  B-operand
    const _Float16* __restrict__ WtP,   // packed (24 x 768 x 32) A-operand
    const float* __restrict__ bias,     // (N)
    const float* __restrict__ spart,    // (48 x M6) row-sumsq or nullptr
    _Float16* __restrict__ Cout,        // packed f16 (GELU) or unused
    float* __restrict__ gpart) {        // (32 x 4 x 768) (fc2) or unused
    __shared__ _Float16 lA[3][2][64][32];  // [buf][kb][n][k'']
    __shared__ _Float16 lB[3][2][64][32];  // [buf][kb][m][k'']
    __shared__ float part2[2][2][64];      // [wmhalf][seg][n]  (fc2 only)
    __shared__ float invS[64];             // (fc1 only)
    const int tid = threadIdx.x;
    const int w = tid >> 6, l = tid & 63;
    const int l15 = l & 15, lk = l >> 4;

    // XCD swizzle: equal lid%8 (one XCD) covers one m-row's 12 n-tiles.
    const int lid = blockIdx.x;
    int vm, vn;
    if (lid < 1152) { vm = (lid / 96) * 8 + (lid & 7); vn = (lid % 96) >> 3; }
    else            { const int r = lid - 1152; vm = 96 + r / 12; vn = r % 12; }
    const int m0 = vm * 64, n0 = vn * 64;
    const int wn = (w & 1) * 32, wm = (w >> 1) * 32;

    // fc1: inline inv-norm for this block's 64 rows (fixed-order sum),
    // fully drained BEFORE any gload_lds is issued.
    if constexpr (GELU) {
        if (tid < 64) {
            float s = 0.0f;
#pragma unroll 8
            for (int cb = 0; cb < 48; ++cb)
                s += spart[(size_t)cb * M6 + m0 + tid];
            invS[tid] = 1.0f / fmaxf(sqrtf(s), 1e-12f);
        }
        __syncthreads();                   // drains inv loads (vmcnt -> 0)
    }

    f32x4 acc[2][2] = {};   // [fa over n][fb over m]

    // wave w stages one 4 KB chunk per stage: w<2 -> A (kb = w&1), else B
    const int kbsel = w & 1;
    const bool isB = (w >= 2);
    const _Float16* srcBase =
        isB ? (TokP + (size_t)m0 * 32) : (WtP + (size_t)n0 * 32);
    const size_t tileStride = isB ? (size_t)TM : (size_t)TW;
    _Float16* dst0 = isB ? &lB[0][kbsel][0][0] : &lA[0][kbsel][0][0];

#define ISSUE(tt, bf_)                                                         \
    {   const _Float16* s_ = srcBase + (size_t)(2 * (tt) + kbsel) * tileStride;\
        _Float16* d_ = dst0 + (size_t)(bf_) * 4096;                            \
        GLOAD_LDS16(s_ + l * 8,        d_ + l * 8);                            \
        GLOAD_LDS16(s_ + 512 + l * 8,  d_ + 512 + l * 8);                      \
        GLOAD_LDS16(s_ + 1024 + l * 8, d_ + 1024 + l * 8);                     \
        GLOAD_LDS16(s_ + 1536 + l * 8, d_ + 1536 + l * 8); }

    ISSUE(0, 0); ISSUE(1, 1); ISSUE(2, 2);   // 12 loads in flight / wave

    for (int t = 0; t < NT; ++t) {
        // own-wave tile-t loads complete; t+1, t+2 remain in flight
        if (t < NT - 2)       asm volatile("s_waitcnt vmcnt(8)" ::: "memory");
        else if (t == NT - 2) asm volatile("s_waitcnt vmcnt(4)" ::: "memory");
        else                  asm volatile("s_waitcnt vmcnt(0)" ::: "memory");
        __builtin_amdgcn_s_barrier();          // all waves' tile-t loads done
        __builtin_amdgcn_sched_barrier(0);     // no ds_read hoisted above

        const int buf = t % 3;
#pragma unroll
        for (int kk = 0; kk < 2; ++kk) {       // two 32-k sub-steps (kb tiles)
            half8 af[2], bf[2];
#pragma unroll
            for (int fa = 0; fa < 2; ++fa) {
                const int rowA = wn + fa * 16 + l15;
                const int colA = (lk ^ ((rowA >> 1) & 3)) * 8;   // T2 read
                af[fa] = *(const half8*)&lA[buf][kk][rowA][colA];
            }
#pragma unroll
            for (int fb = 0; fb < 2; ++fb) {
                const int rowB = wm + fb * 16 + l15;
                const int colB = (lk ^ ((rowB >> 1) & 3)) * 8;   // T2 read
                bf[fb] = *(const half8*)&lB[buf][kk][rowB][colB];
            }
#pragma unroll
            for (int fa = 0; fa < 2; ++fa)
#pragma unroll
                for (int fb = 0; fb < 2; ++fb)
                    acc[fa][fb] = __builtin_amdgcn_mfma_f32_16x16x32_f16(
                        af[fa], bf[fb], acc[fa][fb], 0, 0, 0);
        }
        asm volatile("s_waitcnt lgkmcnt(0)" ::: "memory");  // reads retired
        __builtin_amdgcn_s_barrier();          // safe to overwrite buf
        __builtin_amdgcn_sched_barrier(0);
        if (t < NT - 3) ISSUE(t + 3, buf);     // refill; stays in flight
    }
#undef ISSUE

    // epilogue: lane holds D[n = nb + r][m], r=0..3 consecutive n
    const int b0 = m0 / P;
    const int rsplit = (b0 + 1) * P;
    float invm[2];
    if constexpr (GELU) {
#pragma unroll
        for (int fb = 0; fb < 2; ++fb)
            invm[fb] = invS[wm + fb * 16 + l15];
    }
#pragma unroll
    for (int fa = 0; fa < 2; ++fa) {
        const int nb = n0 + wn + fa * 16 + lk * 4;
        const float4 bv = *(const float4*)&bias[nb];
        if constexpr (GELU) {
#pragma unroll
            for (int fb = 0; fb < 2; ++fb) {
                const int m = m0 + wm + fb * 16 + l15;
                half4 o;
#pragma unroll
                for (int rr = 0; rr < 4; ++rr) {
                    float v = acc[fa][fb][rr] * invm[fb] + ((const float*)&bv)[rr];
                    v = 0.5f * v * (1.0f + erff(v * 0.70710678118654752f));
                    o[rr] = (_Float16)v;
                }
                const int el = (nb & 31) ^ (((m >> 1) & 3) << 3);
                *(half4*)&Cout[(size_t)(nb >> 5) * TM + (size_t)m * 32 + el] = o;
            }
        } else {
#pragma unroll
            for (int rr = 0; rr < 4; ++rr) {
                float s0 = 0.0f, s1 = 0.0f;
#pragma unroll
                for (int fb = 0; fb < 2; ++fb) {
                    const int m = m0 + wm + fb * 16 + l15;
                    const float v = acc[fa][fb][rr] + ((const float*)&bv)[rr];
                    const float u = fmaxf(v, 1e-6f);
                    const float u3 = u * u * u;
                    if (m >= rsplit) s1 += u3; else s0 += u3;
                }
                s0 += __shfl_xor(s0, 1); s0 += __shfl_xor(s0, 2);
                s0 += __shfl_xor(s0, 4); s0 += __shfl_xor(s0, 8);
                s1 += __shfl_xor(s1, 1); s1 += __shfl_xor(s1, 2);
                s1 += __shfl_xor(s1, 4); s1 += __shfl_xor(s1, 8);
                if (l15 == 0) {
                    part2[w >> 1][0][wn + fa * 16 + lk * 4 + rr] = s0;
                    part2[w >> 1][1][wn + fa * 16 + lk * 4 + rr] = s1;
                }
            }
        }
    }
    if constexpr (!GELU) {
        __syncthreads();
        if (tid < 128) {
            const int seg = tid >> 6, nn = tid & 63;
            const float tot = part2[0][seg][nn] + part2[1][seg][nn];
            if (seg == 0) {
                const int q = vm - ((b0 * 49) >> 4);   // vm - first_vm(b0)
                gpart[((size_t)b0 * 4 + q) * C + n0 + nn] = tot;
            } else if (rsplit < m0 + 64) {             // straddling block
                gpart[((size_t)(b0 + 1) * 4 + 0) * C + n0 + nn] = tot;
            }
        }
    }
}

// ---------------------------------------------------------------------------
// K6a: head GEMM stage 1 (split-K, 64 k per block) with FUSED GeM combine:
// g[b][k] = cbrt(mean of 4 fixed-order gpart slots) computed on the fly.
// grid (64, 12).
// ---------------------------------------------------------------------------
__global__ __launch_bounds__(256) void k_head1(const float* __restrict__ gpart,
                                               const float* __restrict__ W,
                                               float* __restrict__ partial) {
    const int n0 = blockIdx.x * 64;
    const int k0 = blockIdx.y * 64;
    __shared__ float gs[32][64];          // [b][kk]  8 KB
    __shared__ float part[4][32][64];     // [q][b][c] 32 KB
    const int tid = threadIdx.x;

    for (int idx = tid; idx < 32 * 64; idx += 256) {
        const int b = idx >> 6, kk = idx & 63;
        const float* gp = &gpart[((size_t)b * 4) * C + k0 + kk];
        const float s = gp[0] + gp[C] + gp[2 * C] + gp[3 * C];
        gs[b][kk] = cbrtf(s * (1.0f / (float)P));
    }
    __syncthreads();

    const int c = tid & 63, q = tid >> 6;
    float acc[32] = {};
#pragma unroll
    for (int kk = 0; kk < 16; ++kk) {
        const int k = q * 16 + kk;
        const float wv = W[(size_t)(k0 + k) * NC + n0 + c];
#pragma unroll
        for (int b = 0; b < 32; ++b) acc[b] += gs[b][k] * wv;
    }
#pragma unroll
    for (int b = 0; b < 32; ++b) part[q][b][c] = acc[b];
    __syncthreads();

    for (int o = tid; o < 32 * 64; o += 256) {
        const int b = o >> 6, cc = o & 63;
        const float v = part[0][b][cc] + part[1][b][cc] +
                        part[2][b][cc] + part[3][b][cc];
        partial[((size_t)blockIdx.y * 32 + b) * NC + n0 + cc] = v;
    }
}

// ---------------------------------------------------------------------------
// K6b: head stage 2: fixed-order sum of KSPLIT partials + bias.
// grid (16, 32) = 512 blocks (parallelism matters: one-block-per-batch
// fusion was a 49 us latency stall in R20).
// ---------------------------------------------------------------------------
__global__ __launch_bounds__(256) void k_head2(const float* __restrict__ partial,
                                               const float* __restrict__ hb,
                                               float* __restrict__ out) {
    const int n = blockIdx.x * 256 + threadIdx.x;
    const int b = blockIdx.y;
    float s = hb[n];
#pragma unroll
    for (int ks = 0; ks < KSPLIT; ++ks)
        s += partial[((size_t)ks * 32 + b) * NC + n];
    out[(size_t)b * NC + n] = s;
}

// ---------------------------------------------------------------------------
// K7: L2-normalize each batch row of out (4096) in place.
// ---------------------------------------------------------------------------
__global__ __launch_bounds__(256) void k_outnorm(float* __restrict__ out) {
    const int b = blockIdx.x;
    float* r = out + (size_t)b * NC;
    const int tid = threadIdx.x;
    float v[16];
    float s = 0.0f;
#pragma unroll
    for (int q = 0; q < 16; ++q) {
        v[q] = r[tid + q * 256];
        s += v[q] * v[q];
    }
    __shared__ float partial[4];
    __shared__ float inv;
#pragma unroll
    for (int off = 32; off > 0; off >>= 1) s += __shfl_xor(s, off);
    if ((tid & 63) == 0) partial[tid >> 6] = s;
    __syncthreads();
    if (tid == 0)
        inv = 1.0f / fmaxf(sqrtf(partial[0] + partial[1] + partial[2] + partial[3]), 1e-12f);
    __syncthreads();
#pragma unroll
    for (int q = 0; q < 16; ++q) r[tid + q * 256] = v[q] * inv;
}

// ---------------------------------------------------------------------------
extern "C" void kernel_launch(void* const* d_in, const int* in_sizes, int n_in,
                              void* d_out, int out_size, void* d_ws, size_t ws_size,
                              hipStream_t stream) {
    const float* patch  = (const float*)d_in[0];
    const float* fc1_w  = (const float*)d_in[1];
    const float* fc1_b  = (const float*)d_in[2];
    const float* fc2_w  = (const float*)d_in[3];
    const float* fc2_b  = (const float*)d_in[4];
    const float* head_w = (const float*)d_in[5];
    const float* head_b = (const float*)d_in[6];
    float* out = (float*)d_out;

    const size_t big = (size_t)B * P * C;        // 4,816,896 elements
    _Float16* tokU  = (_Float16*)d_ws;           // [big] f16 packed+swz (unnorm)
    _Float16* hdnP  = tokU + big;                // [big] f16 packed+swz
    _Float16* wt1   = hdnP + big;                // [768*768] f16 packed+swz
    _Float16* wt2   = wt1 + C * C;               // [768*768] f16 packed+swz
    float*    spart = (float*)(wt2 + C * C);     // [48*M6] row-sumsq partials
    float*    gpart = spart + 48 * (size_t)M6;   // [32*4*768] f32
    float*    hpart = gpart + (size_t)B * 4 * C; // [KSPLIT*32*4096] f32

    // K1: SSA (z=0) + weight packs (z=1) in ONE launch
    k_ssa<<<dim3(48, B, 2), dim3(256), 0, stream>>>(
        patch, tokU, spart, fc1_w, fc2_w, wt1, wt2);
    // K3: fc1 (inline inv-norm from spart) + gelu -> hdnP (f16 packed+swz)
    k_mfma_gemm<true><<<dim3(1176), dim3(256), 0, stream>>>(
        tokU, wt1, fc1_b, spart, hdnP, nullptr);
    // K4: fc2 + fused GeM partials -> gpart (no token output)
    k_mfma_gemm<false><<<dim3(1176), dim3(256), 0, stream>>>(
        hdnP, wt2, fc2_b, nullptr, nullptr, gpart);
    // K6a: head GEMM stage 1 (g computed on the fly from gpart)
    k_head1<<<dim3(NC / 64, KSPLIT), dim3(256), 0, stream>>>(
        gpart, head_w, hpart);
    // K6b: head stage 2 -> out
    k_head2<<<dim3(NC / 256, B), dim3(256), 0, stream>>>(hpart, head_b, out);
    // K7: normalize rows of out
    k_outnorm<<<dim3(B), dim3(256), 0, stream>>>(out);
}

// Round 23
// 81.737 us; speedup vs baseline: 1.5501x; 1.0033x over previous
//
#include <hip/hip_runtime.h>
#include <hip/hip_bf16.h>
#include <math.h>

// Problem dims (fixed by reference)
#define B   32
#define P   196      // hw tokens (14x14)
#define C   768
#define NC  4096
#define HH  14
#define KSPLIT 12    // 768 / 64
#define NT  12       // K tiles per GEMM (768 / 64)
#define M6  6272     // B*P
// Packed k-tiled layout with T2 bank swizzle (R17, measured-best):
//   element (row, k) stored at X[kb][row][ k' ^ (((row>>1)&3)<<3) ]
//   (kb = k>>5, k' = k&31).  B staging is a LINEAR 4 KB copy; LDS fragment
//   reads apply the XOR -> 2-way bank conflict (free).  A fragments are
//   read DIRECT from global: lanes {l15,l15+16,l15+32,l15+48} cover each
//   64-B row line -> 1 KB contiguous per load instruction (coalesced).
#define TW  (768 * 32)    // Wt packed kb stride (elements)
#define TM  (M6 * 32)     // Tok/hdn packed kb stride (elements)

typedef _Float16 half8 __attribute__((ext_vector_type(8)));
typedef _Float16 half4 __attribute__((ext_vector_type(4)));
typedef float f32x4 __attribute__((ext_vector_type(4)));

#define GLOAD_LDS16(g, l)                                                      \
    __builtin_amdgcn_global_load_lds(                                          \
        (const __attribute__((address_space(1))) void*)(g),                    \
        (__attribute__((address_space(3))) void*)(l), 16, 0, 0)

// ---------------------------------------------------------------------------
// K1 (merged): z=0 -> SpaceSelfAware + space_fusion + residual + PACK;
// z=1 -> weight pack for both MLP matrices (concurrent, LDS overlay).
// ---------------------------------------------------------------------------
__global__ __launch_bounds__(256) void k_ssa(const float* __restrict__ t,
                                             _Float16* __restrict__ outP,
                                             float* __restrict__ spart,
                                             const float* __restrict__ W1,
                                             const float* __restrict__ W2,
                                             _Float16* __restrict__ O1,
                                             _Float16* __restrict__ O2) {
    __shared__ float xp_[256 * 16];        // [(i+2)*16 + (j+1)][cc]  16 KB
    __shared__ float part[4][9][16];
    __shared__ float inv_norm[9][16];
    __shared__ _Float16 outT[P][16];       // 6.3 KB
    const int tid = threadIdx.x;

    if (blockIdx.z == 1) {                 // ---- weight pack branch ----
        const int idx = blockIdx.y * 48 + blockIdx.x;
        if (idx >= 1152) return;
        const bool second = idx >= 576;
        const int id2 = second ? idx - 576 : idx;
        const float* W = second ? W2 : W1;
        _Float16* WtP = second ? O2 : O1;
        const int kb = id2 / 24, nb2 = id2 % 24;
        const int k0 = kb * 32, n0 = nb2 * 32;
        float (*tt)[33] = (float (*)[33])xp_;   // overlay 32x33 f32
        const int r = tid / 32, c = tid % 32;
#pragma unroll
        for (int q = 0; q < 4; ++q)
            tt[r + q * 8][c] = W[(size_t)(k0 + r + q * 8) * C + n0 + c];
        __syncthreads();
        const int nl = tid >> 3, h = tid & 7;
        const int n = n0 + nl;
        half4 v;
#pragma unroll
        for (int j = 0; j < 4; ++j) v[j] = (_Float16)tt[h * 4 + j][nl];
        const int el = (h * 4) ^ (((n >> 1) & 3) << 3);      // T2 swizzle
        *(half4*)&WtP[(size_t)kb * TW + (size_t)n * 32 + el] = v;
        return;
    }

    // ---- SSA branch ----
    const int b = blockIdx.y, cb = blockIdx.x, c0 = cb * 16;
    const int cc = tid & 15, g = tid >> 4, wv = tid >> 6;

#pragma unroll
    for (int q = 0; q < 16; ++q) xp_[q * 256 + tid] = 0.0f;
    __syncthreads();

    for (int idx = tid; idx < 784; idx += 256) {
        const int p = idx >> 2, c = (idx & 3) * 4;
        const int i = p / HH, j = p % HH;
        *(float4*)&xp_[((i + 2) * 16 + (j + 1)) * 16 + c] =
            *(const float4*)&t[((size_t)b * P + p) * C + c0 + c];
    }
    __syncthreads();

    float s[9] = {};
    {
        int i = 0, j = g;
        if (j >= HH) { j -= HH; i = 1; }
        for (int p = g; p < P; p += 16) {
            const int base = ((i + 2) * 16 + (j + 1)) * 16 + cc;
            const float xp = xp_[base];
            const float xp2 = xp * xp;
#pragma unroll
            for (int k = 0; k < 9; ++k) {
                const int off = ((k / 3) - 2) * 16 + (k % 3) - 1;  // const
                const float nb = xp_[base + off * 16];
                s[k] += xp2 * nb * nb;
            }
            j += 2; ++i;
            if (j >= HH) { j -= HH; ++i; }
        }
    }
#pragma unroll
    for (int k = 0; k < 9; ++k) {
        float r = s[k];
        r += __shfl_xor(r, 16);
        r += __shfl_xor(r, 32);
        s[k] = r;
    }
    if ((tid & 63) < 16) {
#pragma unroll
        for (int k = 0; k < 9; ++k) part[wv][k][cc] = s[k];
    }
    __syncthreads();
    if (tid < 144) {
        const int k = tid >> 4, c2 = tid & 15;
        const float t4 = part[0][k][c2] + part[1][k][c2] +
                         part[2][k][c2] + part[3][k][c2];
        inv_norm[k][c2] = 1.0f / fmaxf(sqrtf(t4), 1e-12f);
    }
    __syncthreads();

    float invn[9];
#pragma unroll
    for (int k = 0; k < 9; ++k) invn[k] = inv_norm[k][cc];

    {
        int i = 0, j = g;
        if (j >= HH) { j -= HH; i = 1; }
        for (int p = g; p < P; p += 16) {
            const int base = ((i + 2) * 16 + (j + 1)) * 16 + cc;
            const float xp = xp_[base];
            float acc = 0.0f;
#pragma unroll
            for (int k = 0; k < 9; ++k) {
                const int off = ((k / 3) - 2) * 16 + (k % 3) - 1;
                const float v = xp * xp_[base + off * 16];
                const float u = fmaxf(v * invn[k], 1e-6f);
                acc += u * u * u;
            }
            const float val = cbrtf(acc * (1.0f / 9.0f)) + xp;
            float rs = val * val;
            rs += __shfl_xor(rs, 1);
            rs += __shfl_xor(rs, 2);
            rs += __shfl_xor(rs, 4);
            rs += __shfl_xor(rs, 8);
            outT[p][cc] = (_Float16)val;
            if (cc == 0) spart[(size_t)cb * M6 + b * P + p] = rs;
            j += 2; ++i;
            if (j >= HH) { j -= HH; ++i; }
        }
    }
    __syncthreads();
    // pack: 392 half8 stores into tokU[kb][row][swizzled slot]
    const int kb = cb >> 1, kbase = (cb & 1) * 16;
    for (int idx = tid; idx < P * 2; idx += 256) {
        const int p = idx >> 1, h = idx & 1;
        const half8 v = *(const half8*)&outT[p][h * 8];
        const int row = b * P + p;
        const int slot = ((kbase + h * 8) >> 3) ^ ((row >> 1) & 3);   // T2
        *(half8*)&outP[(size_t)kb * TM + (size_t)row * 32 + slot * 8] = v;
    }
}

// ---------------------------------------------------------------------------
// K3/K4: HYBRID f16 MFMA GEMM — A (weights, XCD-L2-resident) read DIRECT
// into named register groups (aW/aX) prefetched one K-step ahead; B (tokens)
// staged via 2-stage gload_lds pipeline.  FIFO discipline: per iteration
// [A(t+1) x4][B(t+2) x2] issued in that order (sched_barrier-pinned), so
// top-of-iter vmcnt(6) retires B(t) and the compiler's A-consume wait is
// vmcnt(2) — B(t+1) never drained.  LDS 17 KB -> all 1176 blocks
// co-resident (~4.6/CU, ~18 waves/CU vs 12 before).
// 64M x 64N, BK=64, XCD swizzle, T2 swizzle on B reads / A addresses.
// GELU=true (fc1): inline inv-norm from spart; acc*inv + bias + GELU ->
// packed+swz f16.  GELU=false (fc2): acc + bias -> fused GeM partials.
// ---------------------------------------------------------------------------
template <bool GELU>
__global__ __launch_bounds__(256, 4) void k_mfma_gemm(
    const _Float16* __restrict__ TokP,  // packed (24 x M6 x 32)  B-operand
    const _Float16* __restrict__ WtP,   // packed (24 x 768 x 32) A-operand
    const float* __restrict__ bias,     // (N)
    const float* __restrict__ spart,    // (48 x M6) row-sumsq or nullptr
    _Float16* __restrict__ Cout,        // packed f16 (GELU) or unused
    float* __restrict__ gpart) {        // (32 x 4 x 768) (fc2) or unused
    __shared__ _Float16 lB[2][2][64][32];  // [stage][kb][m][k'']  16 KB
    __shared__ float part2[2][2][64];      // [wmhalf][seg][n]  (fc2 only)
    __shared__ float invS[64];             // (fc1 only)
    const int tid = threadIdx.x;
    const int w = tid >> 6, l = tid & 63;
    const int l15 = l & 15, lk = l >> 4;

    // XCD swizzle: equal lid%8 (one XCD) covers one m-row's 12 n-tiles.
    const int lid = blockIdx.x;
    int vm, vn;
    if (lid < 1152) { vm = (lid / 96) * 8 + (lid & 7); vn = (lid % 96) >> 3; }
    else            { const int r = lid - 1152; vm = 96 + r / 12; vn = r % 12; }
    const int m0 = vm * 64, n0 = vn * 64;
    const int wn = (w & 1) * 32, wm = (w >> 1) * 32;

    // fc1: inline inv-norm for this block's 64 rows (fixed-order sum),
    // fully drained BEFORE any pipeline load is issued.
    if constexpr (GELU) {
        if (tid < 64) {
            float s = 0.0f;
#pragma unroll 8
            for (int cb = 0; cb < 48; ++cb)
                s += spart[(size_t)cb * M6 + m0 + tid];
            invS[tid] = 1.0f / fmaxf(sqrtf(s), 1e-12f);
        }
        __syncthreads();                   // drains inv loads (vmcnt -> 0)
    }

    f32x4 acc[2][2] = {};   // [fa over n][fb over m]

    // ---- B staging: 8 x 1 KB loads per stage; wave w takes q = 2w, 2w+1.
#define ISSUE_B(tt, st_)                                                       \
    {   _Pragma("unroll")                                                      \
        for (int qq = 0; qq < 2; ++qq) {                                       \
            const int q = w * 2 + qq, kbp = q >> 2, ld = q & 3;                \
            const _Float16* s_ = TokP + (size_t)(2 * (tt) + kbp) * TM +        \
                                 (size_t)m0 * 32 + ld * 512;                   \
            GLOAD_LDS16(s_ + l * 8, &lB[st_][kbp][ld * 16][0] + l * 8); }      }

    // ---- A direct fragment loads (global, swizzled address).
#define LOADA(dst, tt)                                                         \
    {   _Pragma("unroll")                                                      \
        for (int kk2 = 0; kk2 < 2; ++kk2)                                      \
        _Pragma("unroll")                                                      \
        for (int fa2 = 0; fa2 < 2; ++fa2) {                                    \
            const int rowA = n0 + wn + fa2 * 16 + l15;                         \
            dst[kk2 * 2 + fa2] = *(const half8*)&WtP[                          \
                (size_t)(2 * (tt) + kk2) * TW + (size_t)rowA * 32 +            \
                ((lk ^ ((rowA >> 1) & 3)) * 8)]; }                             }

#define COMPUTE(st_, aR)                                                       \
    {   _Pragma("unroll")                                                      \
        for (int kk = 0; kk < 2; ++kk) {                                       \
            half8 bf[2];                                                       \
            _Pragma("unroll")                                                  \
            for (int fb = 0; fb < 2; ++fb) {                                   \
                const int rowB = wm + fb * 16 + l15;                           \
                bf[fb] = *(const half8*)&lB[st_][kk][rowB]                     \
                             [(lk ^ ((rowB >> 1) & 3)) * 8];                   \
            }                                                                  \
            _Pragma("unroll")                                                  \
            for (int fa = 0; fa < 2; ++fa)                                     \
            _Pragma("unroll")                                                  \
            for (int fb = 0; fb < 2; ++fb)                                     \
                acc[fa][fb] = __builtin_amdgcn_mfma_f32_16x16x32_f16(          \
                    aR[kk * 2 + fa], bf[fb], acc[fa][fb], 0, 0, 0); }          }

    half8 aW[4], aX[4];
    // prologue FIFO: B(0)x2, A(0)x4, B(1)x2
    ISSUE_B(0, 0);
    __builtin_amdgcn_sched_barrier(0);
    LOADA(aW, 0);
    __builtin_amdgcn_sched_barrier(0);
    ISSUE_B(1, 1);

#pragma unroll
    for (int tt = 0; tt < 6; ++tt) {
        // ---- t = 2tt (stage 0, group W) ----
        asm volatile("s_waitcnt vmcnt(6)" ::: "memory");   // B(t) retired
        __builtin_amdgcn_s_barrier();
        __builtin_amdgcn_sched_barrier(0);
        COMPUTE(0, aW);
        asm volatile("s_waitcnt lgkmcnt(0)" ::: "memory");
        __builtin_amdgcn_s_barrier();
        __builtin_amdgcn_sched_barrier(0);
        LOADA(aX, 2 * tt + 1);                              // A(t+1)
        __builtin_amdgcn_sched_barrier(0);
        if (tt < 5) ISSUE_B(2 * tt + 2, 0);                 // B(t+2)

        // ---- t = 2tt+1 (stage 1, group X) ----
        if (tt < 5) asm volatile("s_waitcnt vmcnt(6)" ::: "memory");
        else        asm volatile("s_waitcnt vmcnt(4)" ::: "memory");
        __builtin_amdgcn_s_barrier();
        __builtin_amdgcn_sched_barrier(0);
        COMPUTE(1, aX);
        asm volatile("s_waitcnt lgkmcnt(0)" ::: "memory");
        __builtin_amdgcn_s_barrier();
        __builtin_amdgcn_sched_barrier(0);
        if (tt < 5) {
            LOADA(aW, 2 * tt + 2);                          // A(t+1)
            __builtin_amdgcn_sched_barrier(0);
            ISSUE_B(2 * tt + 3, 1);                         // B(t+2)
        }
    }
#undef ISSUE_B
#undef LOADA
#undef COMPUTE

    // epilogue: lane holds D[n = nb + r][m], r=0..3 consecutive n
    const int b0 = m0 / P;
    const int rsplit = (b0 + 1) * P;
    float invm[2];
    if constexpr (GELU) {
#pragma unroll
        for (int fb = 0; fb < 2; ++fb)
            invm[fb] = invS[wm + fb * 16 + l15];
    }
#pragma unroll
    for (int fa = 0; fa < 2; ++fa) {
        const int nb = n0 + wn + fa * 16 + lk * 4;
        const float4 bv = *(const float4*)&bias[nb];
        if constexpr (GELU) {
#pragma unroll
            for (int fb = 0; fb < 2; ++fb) {
                const int m = m0 + wm + fb * 16 + l15;
                half4 o;
#pragma unroll
                for (int rr = 0; rr < 4; ++rr) {
                    float v = acc[fa][fb][rr] * invm[fb] + ((const float*)&bv)[rr];
                    v = 0.5f * v * (1.0f + erff(v * 0.70710678118654752f));
                    o[rr] = (_Float16)v;
                }
                const int el = (nb & 31) ^ (((m >> 1) & 3) << 3);
                *(half4*)&Cout[(size_t)(nb >> 5) * TM + (size_t)m * 32 + el] = o;
            }
        } else {
#pragma unroll
            for (int rr = 0; rr < 4; ++rr) {
                float s0 = 0.0f, s1 = 0.0f;
#pragma unroll
                for (int fb = 0; fb < 2; ++fb) {
                    const int m = m0 + wm + fb * 16 + l15;
                    const float v = acc[fa][fb][rr] + ((const float*)&bv)[rr];
                    const float u = fmaxf(v, 1e-6f);
                    const float u3 = u * u * u;
                    if (m >= rsplit) s1 += u3; else s0 += u3;
                }
                s0 += __shfl_xor(s0, 1); s0 += __shfl_xor(s0, 2);
                s0 += __shfl_xor(s0, 4); s0 += __shfl_xor(s0, 8);
                s1 += __shfl_xor(s1, 1); s1 += __shfl_xor(s1, 2);
                s1 += __shfl_xor(s1, 4); s1 += __shfl_xor(s1, 8);
                if (l15 == 0) {
                    part2[w >> 1][0][wn + fa * 16 + lk * 4 + rr] = s0;
                    part2[w >> 1][1][wn + fa * 16 + lk * 4 + rr] = s1;
                }
            }
        }
    }
    if constexpr (!GELU) {
        __syncthreads();
        if (tid < 128) {
            const int seg = tid >> 6, nn = tid & 63;
            const float tot = part2[0][seg][nn] + part2[1][seg][nn];
            if (seg == 0) {
                const int q = vm - ((b0 * 49) >> 4);   // vm - first_vm(b0)
                gpart[((size_t)b0 * 4 + q) * C + n0 + nn] = tot;
            } else if (rsplit < m0 + 64) {             // straddling block
                gpart[((size_t)(b0 + 1) * 4 + 0) * C + n0 + nn] = tot;
            }
        }
    }
}

// ---------------------------------------------------------------------------
// K6a: head GEMM stage 1 (split-K, 64 k per block) with FUSED GeM combine:
// g[b][k] = cbrt(mean of 4 fixed-order gpart slots) computed on the fly.
// grid (64, 12).
// ---------------------------------------------------------------------------
__global__ __launch_bounds__(256) void k_head1(const float* __restrict__ gpart,
                                               const float* __restrict__ W,
                                               float* __restrict__ partial) {
    const int n0 = blockIdx.x * 64;
    const int k0 = blockIdx.y * 64;
    __shared__ float gs[32][64];          // [b][kk]  8 KB
    __shared__ float part[4][32][64];     // [q][b][c] 32 KB
    const int tid = threadIdx.x;

    for (int idx = tid; idx < 32 * 64; idx += 256) {
        const int b = idx >> 6, kk = idx & 63;
        const float* gp = &gpart[((size_t)b * 4) * C + k0 + kk];
        const float s = gp[0] + gp[C] + gp[2 * C] + gp[3 * C];
        gs[b][kk] = cbrtf(s * (1.0f / (float)P));
    }
    __syncthreads();

    const int c = tid & 63, q = tid >> 6;
    float acc[32] = {};
#pragma unroll
    for (int kk = 0; kk < 16; ++kk) {
        const int k = q * 16 + kk;
        const float wv = W[(size_t)(k0 + k) * NC + n0 + c];
#pragma unroll
        for (int b = 0; b < 32; ++b) acc[b] += gs[b][k] * wv;
    }
#pragma unroll
    for (int b = 0; b < 32; ++b) part[q][b][c] = acc[b];
    __syncthreads();

    for (int o = tid; o < 32 * 64; o += 256) {
        const int b = o >> 6, cc = o & 63;
        const float v = part[0][b][cc] + part[1][b][cc] +
                        part[2][b][cc] + part[3][b][cc];
        partial[((size_t)blockIdx.y * 32 + b) * NC + n0 + cc] = v;
    }
}

// ---------------------------------------------------------------------------
// K6b: head stage 2: fixed-order sum of KSPLIT partials + bias.
// grid (16, 32) = 512 blocks.
// ---------------------------------------------------------------------------
__global__ __launch_bounds__(256) void k_head2(const float* __restrict__ partial,
                                               const float* __restrict__ hb,
                                               float* __restrict__ out) {
    const int n = blockIdx.x * 256 + threadIdx.x;
    const int b = blockIdx.y;
    float s = hb[n];
#pragma unroll
    for (int ks = 0; ks < KSPLIT; ++ks)
        s += partial[((size_t)ks * 32 + b) * NC + n];
    out[(size_t)b * NC + n] = s;
}

// ---------------------------------------------------------------------------
// K7: L2-normalize each batch row of out (4096) in place.
// ---------------------------------------------------------------------------
__global__ __launch_bounds__(256) void k_outnorm(float* __restrict__ out) {
    const int b = blockIdx.x;
    float* r = out + (size_t)b * NC;
    const int tid = threadIdx.x;
    float v[16];
    float s = 0.0f;
#pragma unroll
    for (int q = 0; q < 16; ++q) {
        v[q] = r[tid + q * 256];
        s += v[q] * v[q];
    }
    __shared__ float partial[4];
    __shared__ float inv;
#pragma unroll
    for (int off = 32; off > 0; off >>= 1) s += __shfl_xor(s, off);
    if ((tid & 63) == 0) partial[tid >> 6] = s;
    __syncthreads();
    if (tid == 0)
        inv = 1.0f / fmaxf(sqrtf(partial[0] + partial[1] + partial[2] + partial[3]), 1e-12f);
    __syncthreads();
#pragma unroll
    for (int q = 0; q < 16; ++q) r[tid + q * 256] = v[q] * inv;
}

// ---------------------------------------------------------------------------
extern "C" void kernel_launch(void* const* d_in, const int* in_sizes, int n_in,
                              void* d_out, int out_size, void* d_ws, size_t ws_size,
                              hipStream_t stream) {
    const float* patch  = (const float*)d_in[0];
    const float* fc1_w  = (const float*)d_in[1];
    const float* fc1_b  = (const float*)d_in[2];
    const float* fc2_w  = (const float*)d_in[3];
    const float* fc2_b  = (const float*)d_in[4];
    const float* head_w = (const float*)d_in[5];
    const float* head_b = (const float*)d_in[6];
    float* out = (float*)d_out;

    const size_t big = (size_t)B * P * C;        // 4,816,896 elements
    _Float16* tokU  = (_Float16*)d_ws;           // [big] f16 packed+swz (unnorm)
    _Float16* hdnP  = tokU + big;                // [big] f16 packed+swz
    _Float16* wt1   = hdnP + big;                // [768*768] f16 packed+swz
    _Float16* wt2   = wt1 + C * C;               // [768*768] f16 packed+swz
    float*    spart = (float*)(wt2 + C * C);     // [48*M6] row-sumsq partials
    float*    gpart = spart + 48 * (size_t)M6;   // [32*4*768] f32
    float*    hpart = gpart + (size_t)B * 4 * C; // [KSPLIT*32*4096] f32

    // K1: SSA (z=0) + weight packs (z=1) in ONE launch
    k_ssa<<<dim3(48, B, 2), dim3(256), 0, stream>>>(
        patch, tokU, spart, fc1_w, fc2_w, wt1, wt2);
    // K3: fc1 (inline inv-norm from spart) + gelu -> hdnP (f16 packed+swz)
    k_mfma_gemm<true><<<dim3(1176), dim3(256), 0, stream>>>(
        tokU, wt1, fc1_b, spart, hdnP, nullptr);
    // K4: fc2 + fused GeM partials -> gpart (no token output)
    k_mfma_gemm<false><<<dim3(1176), dim3(256), 0, stream>>>(
        hdnP, wt2, fc2_b, nullptr, nullptr, gpart);
    // K6a: head GEMM stage 1 (g computed on the fly from gpart)
    k_head1<<<dim3(NC / 64, KSPLIT), dim3(256), 0, stream>>>(
        gpart, head_w, hpart);
    // K6b: head stage 2 -> out
    k_head2<<<dim3(NC / 256, B), dim3(256), 0, stream>>>(hpart, head_b, out);
    // K7: normalize rows of out
    k_outnorm<<<dim3(B), dim3(256), 0, stream>>>(out);
}